// Round 8
// baseline (123.077 us; speedup 1.0000x reference)
//
#include <hip/hip_runtime.h>

#define NPTS 8192      // H*W
#define BCLS 4         // C
#define NP   6         // B*(C-1) pairs
#define R2   9.0f
#define RAD  3.0f
#define GRD  64
#define NCELL (GRD*GRD)
#define LDSK 2048      // LDS kept-center accumulator cap (overflow -> global)
#define OWNMAX 8       // ceil(NPTS/1024) owned candidates per thread

#define ST_U 0
#define ST_A 1
#define ST_D 2

// ---------------------------------------------------------------------------
// One block per (batch, class) pair. cell >= 2*RAD => radius window spans
// <= 2x2 cells; a row's cells are contiguous in sortid => each scan = TWO flat
// [s,e) loops. Hot loops run in grid-sorted order (lanes spatially coherent).
// P4 is a barrier-free spin-dataflow fixed point: monotone st U->{A,D} means
// stale LDS reads are only conservative; the globally least undecided index
// always has all predecessors decided, and its owner re-scans it every spin
// iteration => it resolves in one pass => chain drains at LDS latency, no
// __syncthreads per generation. volatile st reads defeat register caching.
// Decisions bit-match the sequential greedy (same _rn arithmetic, strict <,
// ascending-index tie-breaks). Spin cap falls back to proven barrier sweeps.
// ---------------------------------------------------------------------------
__global__ __launch_bounds__(1024) void k_fused(
    const float* __restrict__ seg, const float* __restrict__ lidar,
    float* __restrict__ sumx, float* __restrict__ sumy, float* __restrict__ cntw,
    float* __restrict__ out)
{
    const int p = blockIdx.x;
    const int b = p / 3, cls = p % 3 + 1;
    const int tid = threadIdx.x, lane = tid & 63, wv = tid >> 6;
    const int base = p * NPTS;

    __shared__ float2 sp[NPTS];                 // 64 KB
    __shared__ unsigned short cidx[NPTS];       // 16 KB candidate -> pixel
    __shared__ unsigned short sortid[NPTS];     // 16 KB grid order
    __shared__ unsigned int cellpack[NCELL];    // 16 KB start<<16 | cnt
    __shared__ unsigned char st[NPTS];          //  8 KB
    __shared__ float ksx[LDSK], ksy[LDSK], kcn[LDSK];  // 24 KB
    __shared__ unsigned long long ballots[128]; //  1 KB (mask words / kept words)
    __shared__ unsigned int base128[128];       // 512 B (prefix)
    __shared__ unsigned int wtot[16];
    __shared__ float redbuf[4][16];
    __shared__ float sbminx, sbminy, scell;
    __shared__ int sM, sK;

    volatile unsigned char* vst = (volatile unsigned char*)st;
    float* ok = out + (size_t)2 * NP * NPTS + base;

    // ---- P0: zeroing (LDS + output slice; global sums zeroed on demand) ----
    for (int k = tid; k < NPTS; k += 1024) { st[k] = ST_U; ok[k] = 0.f; }
    {
        float2* oc = (float2*)(out + (size_t)2 * base);
        for (int k = tid; k < NPTS; k += 1024) oc[k] = make_float2(0.f, 0.f);
    }
    for (int k = tid; k < NCELL; k += 1024) cellpack[k] = 0u;
    for (int k = tid; k < LDSK; k += 1024) { ksx[k] = 0.f; ksy[k] = 0.f; kcn[k] = 0.f; }

    // ---- P1: argmax + ballot compaction ----
    const float* segb = seg + (size_t)b * BCLS * NPTS;
    const float* lx = lidar + (size_t)b * 2 * NPTS;
    const float* ly = lx + NPTS;
    for (int c0 = 0; c0 < 8; ++c0) {
        int n = c0 * 1024 + tid;
        float bv = segb[n];
        int bc = 0;
        #pragma unroll
        for (int c2 = 1; c2 < BCLS; ++c2) {
            float v = segb[c2 * NPTS + n];
            if (v > bv) { bv = v; bc = c2; }   // strict >: first index wins ties
        }
        unsigned long long bal = __ballot(bc == cls);
        if (lane == 0) ballots[c0 * 16 + wv] = bal;
    }
    __syncthreads();
    if (wv == 0) {                              // wave-scan of 128 popcounts
        unsigned int p0 = (unsigned int)__popcll(ballots[2 * lane]);
        unsigned int p1 = (unsigned int)__popcll(ballots[2 * lane + 1]);
        unsigned int s = p0 + p1, v = s;
        for (int d = 1; d < 64; d <<= 1) {
            unsigned int u = __shfl_up(v, d, 64);
            if (lane >= d) v += u;
        }
        base128[2 * lane] = v - s;
        base128[2 * lane + 1] = v - p1;
        if (lane == 63) sM = (int)v;
    }
    __syncthreads();
    const int M = sM;
    for (int c0 = 0; c0 < 8; ++c0) {
        unsigned long long bal = ballots[c0 * 16 + wv];
        if ((bal >> lane) & 1ull) {
            int n = c0 * 1024 + tid;
            int pos = (int)base128[c0 * 16 + wv] + __popcll(bal & ((1ull << lane) - 1ull));
            sp[pos] = make_float2(lx[n], ly[n]);
            cidx[pos] = (unsigned short)n;
        }
    }
    __syncthreads();

    // ---- P2: bbox -> grid geometry ----
    {
        float mnx = 3e38f, mxx = -3e38f, mny = 3e38f, mxy = -3e38f;
        for (int i = tid; i < M; i += 1024) {
            float2 q = sp[i];
            mnx = fminf(mnx, q.x); mxx = fmaxf(mxx, q.x);
            mny = fminf(mny, q.y); mxy = fmaxf(mxy, q.y);
        }
        for (int d = 32; d; d >>= 1) {
            mnx = fminf(mnx, __shfl_xor(mnx, d, 64));
            mxx = fmaxf(mxx, __shfl_xor(mxx, d, 64));
            mny = fminf(mny, __shfl_xor(mny, d, 64));
            mxy = fmaxf(mxy, __shfl_xor(mxy, d, 64));
        }
        if (lane == 0) { redbuf[0][wv] = mnx; redbuf[1][wv] = mxx;
                         redbuf[2][wv] = mny; redbuf[3][wv] = mxy; }
    }
    __syncthreads();
    if (tid == 0) {
        float a = redbuf[0][0], b2 = redbuf[1][0], c = redbuf[2][0], d = redbuf[3][0];
        for (int q = 1; q < 16; ++q) {
            a = fminf(a, redbuf[0][q]); b2 = fmaxf(b2, redbuf[1][q]);
            c = fminf(c, redbuf[2][q]); d = fmaxf(d, redbuf[3][q]);
        }
        sbminx = a; sbminy = c;
        scell = fmaxf(2.0f * RAD, fmaxf(b2 - a, d - c) / 63.0f);
    }
    __syncthreads();
    const float bminx = sbminx, bminy = sbminy, inv = 1.0f / scell;

    // ---- P3: grid count / scan / scatter (packed start<<16|cnt) ----
    for (int i = tid; i < M; i += 1024) {
        float2 q = sp[i];
        int ix = min(GRD - 1, max(0, (int)((q.x - bminx) * inv)));
        int iy = min(GRD - 1, max(0, (int)((q.y - bminy) * inv)));
        atomicAdd(&cellpack[iy * GRD + ix], 1u);
    }
    __syncthreads();
    {
        unsigned int c4[4], t4 = 0;
        #pragma unroll
        for (int q = 0; q < 4; ++q) { c4[q] = cellpack[tid * 4 + q]; t4 += c4[q]; }
        unsigned int v = t4;
        for (int d = 1; d < 64; d <<= 1) {
            unsigned int u = __shfl_up(v, d, 64);
            if (lane >= d) v += u;
        }
        if (lane == 63) wtot[wv] = v;
        __syncthreads();
        if (tid == 0) {
            unsigned int acc = 0;
            for (int q = 0; q < 16; ++q) { unsigned int t = wtot[q]; wtot[q] = acc; acc += t; }
        }
        __syncthreads();
        unsigned int excl = wtot[wv] + v - t4;
        #pragma unroll
        for (int q = 0; q < 4; ++q) { cellpack[tid * 4 + q] = excl << 16; excl += c4[q]; }
    }
    __syncthreads();
    for (int i = tid; i < M; i += 1024) {
        float2 q = sp[i];
        int ix = min(GRD - 1, max(0, (int)((q.x - bminx) * inv)));
        int iy = min(GRD - 1, max(0, (int)((q.y - bminy) * inv)));
        unsigned int old = atomicAdd(&cellpack[iy * GRD + ix], 1u);
        sortid[(old >> 16) + (old & 0xffffu)] = (unsigned short)i;
    }
    __syncthreads();

    // window rows: [s,e) over sortid, flat + branchless; volatile st reads
    #define ROW_FLAGS(CY, CX0, CX1, I, ME, DEAD, UNDEC)                           \
    {                                                                             \
        unsigned int wa = cellpack[(CY) * GRD + (CX0)];                           \
        unsigned int wb = cellpack[(CY) * GRD + (CX1)];                           \
        unsigned int e0 = wa >> 16, e1 = (wb >> 16) + (wb & 0xffffu);             \
        for (unsigned int e = e0; e < e1; ++e) {                                  \
            int j = sortid[e];                                                    \
            float2 q = sp[j];                                                     \
            unsigned char sv = vst[j];                                            \
            float dx = __fsub_rn(ME.x, q.x), dy = __fsub_rn(ME.y, q.y);           \
            float d2 = __fadd_rn(__fmul_rn(dx, dx), __fmul_rn(dy, dy));           \
            bool in = (d2 < R2) & (j < (I));                                      \
            DEAD  |= in & (sv == ST_A);                                           \
            UNDEC |= in & (sv == ST_U);                                           \
        }                                                                         \
    }
    #define SCAN_FLAGS(I, ME, DEAD, UNDEC)                                        \
    {                                                                             \
        int cx0 = max(0, (int)((ME.x - RAD - bminx) * inv));                      \
        int cx1 = min(GRD - 1, (int)((ME.x + RAD - bminx) * inv));                \
        int cy0 = max(0, (int)((ME.y - RAD - bminy) * inv));                      \
        int cy1 = min(GRD - 1, (int)((ME.y + RAD - bminy) * inv));                \
        DEAD = false; UNDEC = false;                                              \
        ROW_FLAGS(cy0, cx0, cx1, I, ME, DEAD, UNDEC);                             \
        if (cy1 > cy0) ROW_FLAGS(cy1, cx0, cx1, I, ME, DEAD, UNDEC);              \
    }

    // ---- P4: barrier-free spin-dataflow fixed point ----
    {
        int own[OWNMAX];
        float2 ops[OWNMAX];
        int nown = 0;
        for (int g = tid; g < M; g += 1024) {          // grid order: coherent lanes
            int i = sortid[g];
            own[nown] = i;
            ops[nown] = sp[i];
            ++nown;
        }
        int nres = 0;
        for (int spin = 0; nres < nown && spin < (1 << 17); ++spin) {
            for (int k = 0; k < nown; ++k) {
                int i = own[k];
                if (i < 0) continue;
                float2 me = ops[k];
                bool dead, undec;
                SCAN_FLAGS(i, me, dead, undec);
                if (dead)       { st[i] = ST_D; own[k] = -1; ++nres; }
                else if (!undec){ st[i] = ST_A; own[k] = -1; ++nres; }
            }
        }
    }
    // safety net (unreachable): barrier sweeps until no U remains
    for (;;) {
        bool any = false;
        for (int i = tid; i < M; i += 1024) {
            if (st[i] != ST_U) continue;
            float2 me = sp[i];
            bool dead, undec;
            SCAN_FLAGS(i, me, dead, undec);
            if (dead) st[i] = ST_D;
            else if (!undec) st[i] = ST_A;
            else any = true;
        }
        if (__syncthreads_count(any) == 0) break;
    }

    // ---- kept-rank: ballot bitmask + wave-scanned prefix ----
    for (int k = 0; k < 8; ++k) {
        int i = (k << 10) + tid;
        unsigned long long bal = __ballot(st[i] == ST_A);  // st[i>=M] stays ST_U
        if (lane == 0) ballots[(k << 4) + wv] = bal;
    }
    __syncthreads();
    if (wv == 0) {
        unsigned int p0 = (unsigned int)__popcll(ballots[2 * lane]);
        unsigned int p1 = (unsigned int)__popcll(ballots[2 * lane + 1]);
        unsigned int s = p0 + p1, v = s;
        for (int d = 1; d < 64; d <<= 1) {
            unsigned int u = __shfl_up(v, d, 64);
            if (lane >= d) v += u;
        }
        base128[2 * lane] = v - s;
        base128[2 * lane + 1] = v - p1;
        if (lane == 63) sK = (int)v;
    }
    __syncthreads();
    #define KRANK(J) ((int)base128[(J) >> 6] +                                    \
                      __popcll(ballots[(J) >> 6] & ((1ull << ((J) & 63)) - 1ull)))
    if (sK > LDSK) {                            // cold fallback prep: zero globals
        for (int k = tid; k < NPTS; k += 1024) {
            sumx[base + k] = 0.f; sumy[base + k] = 0.f; cntw[base + k] = 0.f;
        }
        __syncthreads();
    }

    // ---- P5: assignment + LDS accumulation (grid order) ----
    #define ROW_ARGMIN(CY, CX0, CX1, ME, BD, BJ)                                  \
    {                                                                             \
        unsigned int wa = cellpack[(CY) * GRD + (CX0)];                           \
        unsigned int wb = cellpack[(CY) * GRD + (CX1)];                           \
        unsigned int e0 = wa >> 16, e1 = (wb >> 16) + (wb & 0xffffu);             \
        for (unsigned int e = e0; e < e1; ++e) {                                  \
            int j = sortid[e];                                                    \
            float2 q = sp[j];                                                     \
            unsigned char sv = st[j];                                             \
            float dx = __fsub_rn(ME.x, q.x), dy = __fsub_rn(ME.y, q.y);           \
            float d2 = __fadd_rn(__fmul_rn(dx, dx), __fmul_rn(dy, dy));           \
            bool better = (sv == ST_A) & ((d2 < BD) | ((d2 == BD) & (j < BJ)));   \
            BD = better ? d2 : BD;                                                \
            BJ = better ? j : BJ;                                                 \
        }                                                                         \
    }
    for (int g = tid; g < M; g += 1024) {
        int i = sortid[g];
        float2 me = sp[i];
        int bj;
        if (st[i] == ST_A) {
            bj = i;                              // self: unique d2 = 0
        } else {
            int cx0 = max(0, (int)((me.x - RAD - bminx) * inv));
            int cx1 = min(GRD - 1, (int)((me.x + RAD - bminx) * inv));
            int cy0 = max(0, (int)((me.y - RAD - bminy) * inv));
            int cy1 = min(GRD - 1, (int)((me.y + RAD - bminy) * inv));
            float bd = 3e38f;
            bj = -1;
            ROW_ARGMIN(cy0, cx0, cx1, me, bd, bj);
            if (cy1 > cy0) ROW_ARGMIN(cy1, cx0, cx1, me, bd, bj);
            if (bj < 0) continue;                // impossible when M > 0
        }
        int r = KRANK(bj);
        if (r < LDSK) {
            atomicAdd(&ksx[r], me.x);
            atomicAdd(&ksy[r], me.y);
            atomicAdd(&kcn[r], 1.0f);
        } else {                                 // cold fallback: global by cand id
            atomicAdd(&sumx[base + bj], me.x);
            atomicAdd(&sumy[base + bj], me.y);
            atomicAdd(&cntw[base + bj], 1.0f);
        }
    }
    __syncthreads();

    // ---- P6: kept candidates overwrite the zeroed output slice ----
    for (int i = tid; i < M; i += 1024) {
        if (st[i] != ST_A) continue;
        int n = cidx[i];
        int r = KRANK(i);
        float sx, sy, c;
        if (r < LDSK) { sx = ksx[r]; sy = ksy[r]; c = kcn[r]; }
        else { sx = sumx[base + i]; sy = sumy[base + i]; c = cntw[base + i]; }
        out[2 * (base + n)]     = sx / c;        // c >= 1 (self-assign)
        out[2 * (base + n) + 1] = sy / c;
        ok[n] = 1.0f;
    }
}

// ---------------------------------------------------------------------------
extern "C" void kernel_launch(void* const* d_in, const int* in_sizes, int n_in,
                              void* d_out, int out_size, void* d_ws, size_t ws_size,
                              hipStream_t stream) {
    const float* seg   = (const float*)d_in[0];   // [B,C,H,W] f32
    const float* lidar = (const float*)d_in[1];   // [B,2,H,W] f32
    float* out = (float*)d_out;

    const size_t A = (size_t)NP * NPTS;           // 49152
    float* sumx = (float*)d_ws;                   // 4A
    float* sumy = sumx + A;                       // 4A
    float* cntw = sumy + A;                       // 4A   (fallback only)

    k_fused<<<NP, 1024, 0, stream>>>(seg, lidar, sumx, sumy, cntw, out);
}

// Round 9
// 118.851 us; speedup vs baseline: 1.0356x; 1.0356x over previous
//
#include <hip/hip_runtime.h>

#define NPTS 8192      // H*W
#define BCLS 4         // C
#define NP   6         // B*(C-1) pairs
#define R2   9.0f
#define RAD  3.0f
#define GRD  64
#define NCELL (GRD*GRD)
#define PCAP 2048      // pending-list capacity (overflow -> sweep fallback)
#define LDSK 2048      // LDS kept-center accumulator cap (overflow -> global)

#define ST_U 0
#define ST_A 1
#define ST_D 2

// Phase-split instrumentation build: identical per-phase logic to the proven
// round-7 fused kernel (59 us), staged as kA (P0-P3) / kB (P4 rounds) /
// kC (P5-P6) so rocprof's per-dispatch dur_us acts as the phase timer.
// Handoff via global scratch; all decision arithmetic unchanged (_rn ops,
// strict <, ascending-index tie-breaks) => bit-identical output.

// window rows: [s,e) over sortid, flat + branchless
#define ROW_FLAGS(CY, CX0, CX1, I, ME, DEAD, UNDEC)                           \
{                                                                             \
    unsigned int wa = cellpack[(CY) * GRD + (CX0)];                           \
    unsigned int wb = cellpack[(CY) * GRD + (CX1)];                           \
    unsigned int e0 = wa >> 16, e1 = (wb >> 16) + (wb & 0xffffu);             \
    for (unsigned int e = e0; e < e1; ++e) {                                  \
        int j = sortid[e];                                                    \
        float2 q = sp[j];                                                     \
        unsigned char sv = st[j];                                             \
        float dx = __fsub_rn(ME.x, q.x), dy = __fsub_rn(ME.y, q.y);           \
        float d2 = __fadd_rn(__fmul_rn(dx, dx), __fmul_rn(dy, dy));           \
        bool in = (d2 < R2) & (j < (I));                                      \
        DEAD  |= in & (sv == ST_A);                                           \
        UNDEC |= in & (sv == ST_U);                                           \
    }                                                                         \
}
#define SCAN_FLAGS(I, ME, DEAD, UNDEC)                                        \
{                                                                             \
    int cx0 = max(0, (int)((ME.x - RAD - bminx) * inv));                      \
    int cx1 = min(GRD - 1, (int)((ME.x + RAD - bminx) * inv));                \
    int cy0 = max(0, (int)((ME.y - RAD - bminy) * inv));                      \
    int cy1 = min(GRD - 1, (int)((ME.y + RAD - bminy) * inv));                \
    DEAD = false; UNDEC = false;                                              \
    ROW_FLAGS(cy0, cx0, cx1, I, ME, DEAD, UNDEC);                             \
    if (cy1 > cy0) ROW_FLAGS(cy1, cx0, cx1, I, ME, DEAD, UNDEC);              \
}

// ---------------------------------------------------------------------------
// kA: P0 zero-out + P1 argmax/compact + P2 bbox + P3 grid build; dump state.
// ---------------------------------------------------------------------------
__global__ __launch_bounds__(1024) void kA(
    const float* __restrict__ seg, const float* __restrict__ lidar,
    float2* __restrict__ g_sp, unsigned short* __restrict__ g_cidx,
    unsigned short* __restrict__ g_sortid, unsigned int* __restrict__ g_cellpack,
    float* __restrict__ g_geom, int* __restrict__ g_M,
    float* __restrict__ out)
{
    const int p = blockIdx.x;
    const int b = p / 3, cls = p % 3 + 1;
    const int tid = threadIdx.x, lane = tid & 63, wv = tid >> 6;
    const int base = p * NPTS;

    __shared__ float2 sp[NPTS];                 // 64 KB
    __shared__ unsigned short cidx[NPTS];       // 16 KB
    __shared__ unsigned short sortid[NPTS];     // 16 KB
    __shared__ unsigned int cellpack[NCELL];    // 16 KB
    __shared__ unsigned long long ballots[128];
    __shared__ unsigned int base128[128];
    __shared__ unsigned int wtot[16];
    __shared__ float redbuf[4][16];
    __shared__ float sbminx, sbminy, scell;
    __shared__ int sM;

    // ---- P0: zero the output slice ----
    float* ok = out + (size_t)2 * NP * NPTS + base;
    for (int k = tid; k < NPTS; k += 1024) ok[k] = 0.f;
    {
        float2* oc = (float2*)(out + (size_t)2 * base);
        for (int k = tid; k < NPTS; k += 1024) oc[k] = make_float2(0.f, 0.f);
    }
    for (int k = tid; k < NCELL; k += 1024) cellpack[k] = 0u;

    // ---- P1: argmax + ballot compaction ----
    const float* segb = seg + (size_t)b * BCLS * NPTS;
    const float* lx = lidar + (size_t)b * 2 * NPTS;
    const float* ly = lx + NPTS;
    for (int c0 = 0; c0 < 8; ++c0) {
        int n = c0 * 1024 + tid;
        float bv = segb[n];
        int bc = 0;
        #pragma unroll
        for (int c2 = 1; c2 < BCLS; ++c2) {
            float v = segb[c2 * NPTS + n];
            if (v > bv) { bv = v; bc = c2; }   // strict >: first index wins ties
        }
        unsigned long long bal = __ballot(bc == cls);
        if (lane == 0) ballots[c0 * 16 + wv] = bal;
    }
    __syncthreads();
    if (wv == 0) {
        unsigned int p0 = (unsigned int)__popcll(ballots[2 * lane]);
        unsigned int p1 = (unsigned int)__popcll(ballots[2 * lane + 1]);
        unsigned int s = p0 + p1, v = s;
        for (int d = 1; d < 64; d <<= 1) {
            unsigned int u = __shfl_up(v, d, 64);
            if (lane >= d) v += u;
        }
        base128[2 * lane] = v - s;
        base128[2 * lane + 1] = v - p1;
        if (lane == 63) sM = (int)v;
    }
    __syncthreads();
    const int M = sM;
    for (int c0 = 0; c0 < 8; ++c0) {
        unsigned long long bal = ballots[c0 * 16 + wv];
        if ((bal >> lane) & 1ull) {
            int n = c0 * 1024 + tid;
            int pos = (int)base128[c0 * 16 + wv] + __popcll(bal & ((1ull << lane) - 1ull));
            sp[pos] = make_float2(lx[n], ly[n]);
            cidx[pos] = (unsigned short)n;
        }
    }
    __syncthreads();

    // ---- P2: bbox -> grid geometry ----
    {
        float mnx = 3e38f, mxx = -3e38f, mny = 3e38f, mxy = -3e38f;
        for (int i = tid; i < M; i += 1024) {
            float2 q = sp[i];
            mnx = fminf(mnx, q.x); mxx = fmaxf(mxx, q.x);
            mny = fminf(mny, q.y); mxy = fmaxf(mxy, q.y);
        }
        for (int d = 32; d; d >>= 1) {
            mnx = fminf(mnx, __shfl_xor(mnx, d, 64));
            mxx = fmaxf(mxx, __shfl_xor(mxx, d, 64));
            mny = fminf(mny, __shfl_xor(mny, d, 64));
            mxy = fmaxf(mxy, __shfl_xor(mxy, d, 64));
        }
        if (lane == 0) { redbuf[0][wv] = mnx; redbuf[1][wv] = mxx;
                         redbuf[2][wv] = mny; redbuf[3][wv] = mxy; }
    }
    __syncthreads();
    if (tid == 0) {
        float a = redbuf[0][0], b2 = redbuf[1][0], c = redbuf[2][0], d = redbuf[3][0];
        for (int q = 1; q < 16; ++q) {
            a = fminf(a, redbuf[0][q]); b2 = fmaxf(b2, redbuf[1][q]);
            c = fminf(c, redbuf[2][q]); d = fmaxf(d, redbuf[3][q]);
        }
        sbminx = a; sbminy = c;
        scell = fmaxf(2.0f * RAD, fmaxf(b2 - a, d - c) / 63.0f);
    }
    __syncthreads();
    const float bminx = sbminx, bminy = sbminy, inv = 1.0f / scell;

    // ---- P3: grid count / scan / scatter ----
    for (int i = tid; i < M; i += 1024) {
        float2 q = sp[i];
        int ix = min(GRD - 1, max(0, (int)((q.x - bminx) * inv)));
        int iy = min(GRD - 1, max(0, (int)((q.y - bminy) * inv)));
        atomicAdd(&cellpack[iy * GRD + ix], 1u);
    }
    __syncthreads();
    {
        unsigned int c4[4], t4 = 0;
        #pragma unroll
        for (int q = 0; q < 4; ++q) { c4[q] = cellpack[tid * 4 + q]; t4 += c4[q]; }
        unsigned int v = t4;
        for (int d = 1; d < 64; d <<= 1) {
            unsigned int u = __shfl_up(v, d, 64);
            if (lane >= d) v += u;
        }
        if (lane == 63) wtot[wv] = v;
        __syncthreads();
        if (tid == 0) {
            unsigned int acc = 0;
            for (int q = 0; q < 16; ++q) { unsigned int t = wtot[q]; wtot[q] = acc; acc += t; }
        }
        __syncthreads();
        unsigned int excl = wtot[wv] + v - t4;
        #pragma unroll
        for (int q = 0; q < 4; ++q) { cellpack[tid * 4 + q] = excl << 16; excl += c4[q]; }
    }
    __syncthreads();
    for (int i = tid; i < M; i += 1024) {
        float2 q = sp[i];
        int ix = min(GRD - 1, max(0, (int)((q.x - bminx) * inv)));
        int iy = min(GRD - 1, max(0, (int)((q.y - bminy) * inv)));
        unsigned int old = atomicAdd(&cellpack[iy * GRD + ix], 1u);
        sortid[(old >> 16) + (old & 0xffffu)] = (unsigned short)i;
    }
    __syncthreads();

    // ---- dump state ----
    for (int k = tid; k < NPTS; k += 1024) {
        g_sp[base + k] = sp[k];
        g_cidx[base + k] = cidx[k];
        g_sortid[base + k] = sortid[k];
    }
    for (int k = tid; k < NCELL; k += 1024) g_cellpack[p * NCELL + k] = cellpack[k];
    if (tid == 0) {
        g_geom[p * 4 + 0] = bminx; g_geom[p * 4 + 1] = bminy; g_geom[p * 4 + 2] = inv;
        g_M[p] = M;
    }
}

// ---------------------------------------------------------------------------
// kB: P4 rounds (round-0 sweep + pending-list rounds). Reads state, writes st.
// ---------------------------------------------------------------------------
__global__ __launch_bounds__(1024) void kB(
    const float2* __restrict__ g_sp, const unsigned short* __restrict__ g_sortid,
    const unsigned int* __restrict__ g_cellpack, const float* __restrict__ g_geom,
    const int* __restrict__ g_M, unsigned char* __restrict__ g_st)
{
    const int p = blockIdx.x;
    const int tid = threadIdx.x, lane = tid & 63;
    const int base = p * NPTS;

    __shared__ float2 sp[NPTS];                 // 64 KB
    __shared__ unsigned short sortid[NPTS];     // 16 KB
    __shared__ unsigned int cellpack[NCELL];    // 16 KB
    __shared__ unsigned char st[NPTS];          //  8 KB
    __shared__ unsigned short plist[2][PCAP];   //  8 KB
    __shared__ int pcnt[2];

    for (int k = tid; k < NPTS; k += 1024) {
        sp[k] = g_sp[base + k];
        sortid[k] = g_sortid[base + k];
        st[k] = ST_U;
    }
    for (int k = tid; k < NCELL; k += 1024) cellpack[k] = g_cellpack[p * NCELL + k];
    if (tid == 0) { pcnt[0] = 0; pcnt[1] = 0; }
    const int M = g_M[p];
    const float bminx = g_geom[p * 4 + 0], bminy = g_geom[p * 4 + 1],
                inv = g_geom[p * 4 + 2];
    __syncthreads();

    // round 0: full sweep in grid order, wave-ordered pending append
    for (int g = tid; g < M; g += 1024) {
        int i = sortid[g];
        float2 me = sp[i];
        bool dead, undec;
        SCAN_FLAGS(i, me, dead, undec);
        if (dead) st[i] = ST_D;
        else if (!undec) st[i] = ST_A;
        bool pendf = !dead && undec;
        unsigned long long act = __ballot(true);
        unsigned long long bal = __ballot(pendf);
        int leader = __builtin_ctzll(act);
        int cnt = __popcll(bal);
        int wbase = 0;
        if (lane == leader && cnt) wbase = atomicAdd(&pcnt[0], cnt);
        wbase = __shfl(wbase, leader, 64);
        if (pendf) {
            int pos = wbase + __popcll(bal & ((1ull << lane) - 1ull));
            if (pos < PCAP) plist[0][pos] = (unsigned short)i;
        }
    }

    int cur = 0;
    for (int round = 0; round < NPTS; ++round) {
        __syncthreads();
        int pc = pcnt[cur];
        if (pc == 0) break;
        if (pc > PCAP) {                        // overflow fallback: full sweeps
            for (;;) {
                bool any = false;
                __syncthreads();
                for (int i = tid; i < M; i += 1024) {
                    if (st[i] != ST_U) continue;
                    float2 me = sp[i];
                    bool dead, undec;
                    SCAN_FLAGS(i, me, dead, undec);
                    if (dead) st[i] = ST_D;
                    else if (!undec) st[i] = ST_A;
                    else any = true;
                }
                if (__syncthreads_count(any) == 0) break;
            }
            break;
        }
        if (tid == 0) pcnt[cur ^ 1] = 0;
        __syncthreads();
        for (int idx = tid; idx < pc; idx += 1024) {
            int i = plist[cur][idx];
            float2 me = sp[i];
            bool dead, undec;
            SCAN_FLAGS(i, me, dead, undec);
            if (dead) st[i] = ST_D;
            else if (!undec) st[i] = ST_A;
            bool pendf = !dead && undec;
            unsigned long long act = __ballot(true);
            unsigned long long bal = __ballot(pendf);
            int leader = __builtin_ctzll(act);
            int cnt = __popcll(bal);
            int wbase = 0;
            if (lane == leader && cnt) wbase = atomicAdd(&pcnt[cur ^ 1], cnt);
            wbase = __shfl(wbase, leader, 64);
            if (pendf) {
                int pos = wbase + __popcll(bal & ((1ull << lane) - 1ull));
                if (pos < PCAP) plist[cur ^ 1][pos] = (unsigned short)i;
            }
        }
        cur ^= 1;
    }
    __syncthreads();
    for (int k = tid; k < NPTS; k += 1024) g_st[base + k] = st[k];
}

// ---------------------------------------------------------------------------
// kC: kept-rank + P5 assignment/accumulate + P6 output.
// ---------------------------------------------------------------------------
__global__ __launch_bounds__(1024) void kC(
    const float2* __restrict__ g_sp, const unsigned short* __restrict__ g_cidx,
    const unsigned short* __restrict__ g_sortid, const unsigned int* __restrict__ g_cellpack,
    const float* __restrict__ g_geom, const int* __restrict__ g_M,
    const unsigned char* __restrict__ g_st,
    float* __restrict__ sumx, float* __restrict__ sumy, float* __restrict__ cntw,
    float* __restrict__ out)
{
    const int p = blockIdx.x;
    const int tid = threadIdx.x, lane = tid & 63, wv = tid >> 6;
    const int base = p * NPTS;

    __shared__ float2 sp[NPTS];                 // 64 KB
    __shared__ unsigned short cidx[NPTS];       // 16 KB
    __shared__ unsigned short sortid[NPTS];     // 16 KB
    __shared__ unsigned int cellpack[NCELL];    // 16 KB
    __shared__ unsigned char st[NPTS];          //  8 KB
    __shared__ float ksx[LDSK], ksy[LDSK], kcn[LDSK];  // 24 KB
    __shared__ unsigned long long ballots[128];
    __shared__ unsigned int base128[128];
    __shared__ int sK;

    for (int k = tid; k < NPTS; k += 1024) {
        sp[k] = g_sp[base + k];
        cidx[k] = g_cidx[base + k];
        sortid[k] = g_sortid[base + k];
        st[k] = g_st[base + k];
    }
    for (int k = tid; k < NCELL; k += 1024) cellpack[k] = g_cellpack[p * NCELL + k];
    for (int k = tid; k < LDSK; k += 1024) { ksx[k] = 0.f; ksy[k] = 0.f; kcn[k] = 0.f; }
    const int M = g_M[p];
    const float bminx = g_geom[p * 4 + 0], bminy = g_geom[p * 4 + 1],
                inv = g_geom[p * 4 + 2];
    __syncthreads();

    // kept-rank: ballot bitmask + wave-scanned prefix
    for (int k = 0; k < 8; ++k) {
        int i = (k << 10) + tid;
        unsigned long long bal = __ballot(st[i] == ST_A);
        if (lane == 0) ballots[(k << 4) + wv] = bal;
    }
    __syncthreads();
    if (wv == 0) {
        unsigned int p0 = (unsigned int)__popcll(ballots[2 * lane]);
        unsigned int p1 = (unsigned int)__popcll(ballots[2 * lane + 1]);
        unsigned int s = p0 + p1, v = s;
        for (int d = 1; d < 64; d <<= 1) {
            unsigned int u = __shfl_up(v, d, 64);
            if (lane >= d) v += u;
        }
        base128[2 * lane] = v - s;
        base128[2 * lane + 1] = v - p1;
        if (lane == 63) sK = (int)v;
    }
    __syncthreads();
    #define KRANK(J) ((int)base128[(J) >> 6] +                                    \
                      __popcll(ballots[(J) >> 6] & ((1ull << ((J) & 63)) - 1ull)))
    if (sK > LDSK) {                            // cold fallback prep: zero globals
        for (int k = tid; k < NPTS; k += 1024) {
            sumx[base + k] = 0.f; sumy[base + k] = 0.f; cntw[base + k] = 0.f;
        }
        __syncthreads();
    }

    // P5: assignment + LDS accumulation (grid order)
    #define ROW_ARGMIN(CY, CX0, CX1, ME, BD, BJ)                                  \
    {                                                                             \
        unsigned int wa = cellpack[(CY) * GRD + (CX0)];                           \
        unsigned int wb = cellpack[(CY) * GRD + (CX1)];                           \
        unsigned int e0 = wa >> 16, e1 = (wb >> 16) + (wb & 0xffffu);             \
        for (unsigned int e = e0; e < e1; ++e) {                                  \
            int j = sortid[e];                                                    \
            float2 q = sp[j];                                                     \
            unsigned char sv = st[j];                                             \
            float dx = __fsub_rn(ME.x, q.x), dy = __fsub_rn(ME.y, q.y);           \
            float d2 = __fadd_rn(__fmul_rn(dx, dx), __fmul_rn(dy, dy));           \
            bool better = (sv == ST_A) & ((d2 < BD) | ((d2 == BD) & (j < BJ)));   \
            BD = better ? d2 : BD;                                                \
            BJ = better ? j : BJ;                                                 \
        }                                                                         \
    }
    for (int g = tid; g < M; g += 1024) {
        int i = sortid[g];
        float2 me = sp[i];
        int bj;
        if (st[i] == ST_A) {
            bj = i;                              // self: unique d2 = 0
        } else {
            int cx0 = max(0, (int)((me.x - RAD - bminx) * inv));
            int cx1 = min(GRD - 1, (int)((me.x + RAD - bminx) * inv));
            int cy0 = max(0, (int)((me.y - RAD - bminy) * inv));
            int cy1 = min(GRD - 1, (int)((me.y + RAD - bminy) * inv));
            float bd = 3e38f;
            bj = -1;
            ROW_ARGMIN(cy0, cx0, cx1, me, bd, bj);
            if (cy1 > cy0) ROW_ARGMIN(cy1, cx0, cx1, me, bd, bj);
            if (bj < 0) continue;                // impossible when M > 0
        }
        int r = KRANK(bj);
        if (r < LDSK) {
            atomicAdd(&ksx[r], me.x);
            atomicAdd(&ksy[r], me.y);
            atomicAdd(&kcn[r], 1.0f);
        } else {
            atomicAdd(&sumx[base + bj], me.x);
            atomicAdd(&sumy[base + bj], me.y);
            atomicAdd(&cntw[base + bj], 1.0f);
        }
    }
    __syncthreads();

    // P6: kept candidates overwrite the zeroed output slice
    float* ok = out + (size_t)2 * NP * NPTS + base;
    for (int i = tid; i < M; i += 1024) {
        if (st[i] != ST_A) continue;
        int n = cidx[i];
        int r = KRANK(i);
        float sx, sy, c;
        if (r < LDSK) { sx = ksx[r]; sy = ksy[r]; c = kcn[r]; }
        else { sx = sumx[base + i]; sy = sumy[base + i]; c = cntw[base + i]; }
        out[2 * (base + n)]     = sx / c;        // c >= 1 (self-assign)
        out[2 * (base + n) + 1] = sy / c;
        ok[n] = 1.0f;
    }
}

// ---------------------------------------------------------------------------
extern "C" void kernel_launch(void* const* d_in, const int* in_sizes, int n_in,
                              void* d_out, int out_size, void* d_ws, size_t ws_size,
                              hipStream_t stream) {
    const float* seg   = (const float*)d_in[0];   // [B,C,H,W] f32
    const float* lidar = (const float*)d_in[1];   // [B,2,H,W] f32
    float* out = (float*)d_out;

    const size_t A = (size_t)NP * NPTS;           // 49152
    char* ws = (char*)d_ws;
    float* sumx = (float*)ws;                                   // 4A (fallback)
    float* sumy = sumx + A;                                     // 4A
    float* cntw = sumy + A;                                     // 4A
    float2* g_sp = (float2*)(cntw + A);                         // 8A
    unsigned int* g_cellpack = (unsigned int*)(g_sp + A);       // NP*NCELL u32
    float* g_geom = (float*)(g_cellpack + (size_t)NP * NCELL);  // 24 f32
    int* g_M = (int*)(g_geom + 4 * NP);                         // NP i32
    unsigned short* g_cidx = (unsigned short*)(g_M + 16);       // 2A
    unsigned short* g_sortid = g_cidx + A;                      // 2A
    unsigned char* g_st = (unsigned char*)(g_sortid + A);       // A
    // total ws use: ~1.6 MB

    kA<<<NP, 1024, 0, stream>>>(seg, lidar, g_sp, g_cidx, g_sortid,
                                g_cellpack, g_geom, g_M, out);
    kB<<<NP, 1024, 0, stream>>>(g_sp, g_sortid, g_cellpack, g_geom, g_M, g_st);
    kC<<<NP, 1024, 0, stream>>>(g_sp, g_cidx, g_sortid, g_cellpack, g_geom, g_M,
                                g_st, sumx, sumy, cntw, out);
}